// Round 12
// baseline (1307.971 us; speedup 1.0000x reference)
//
#include <hip/hip_runtime.h>
#include <hip/hip_bf16.h>

#define NN 50000    // nodes
#define NE 100000   // edges
#define NG 2048     // graphs
#define NF 14
#define D 64
#define EB 128      // edges per block in msg kernel

typedef __attribute__((ext_vector_type(8))) short bf16x8;
typedef __attribute__((ext_vector_type(4))) float f32x4;

__device__ __forceinline__ float sigmoidf(float x) { return 1.f / (1.f + expf(-x)); }

// ---------------- utility ----------------
__global__ void cvt_bf16_kernel(const float* __restrict__ src, __hip_bfloat16* __restrict__ dst, int n) {
    int i = blockIdx.x * 256 + threadIdx.x;
    if (i < n) dst[i] = __float2bfloat16(src[i]);
}

// dst[c*rows + r] = bf16(src[r*cols + c])  (transpose + cast)
__global__ void tcast_bf16_kernel(const float* __restrict__ src, __hip_bfloat16* __restrict__ dst,
                                  int rows, int cols) {
    int idx = blockIdx.x * 256 + threadIdx.x;
    if (idx < rows * cols) {
        int r = idx / cols, c = idx - r * cols;
        dst[c * rows + r] = __float2bfloat16(src[idx]);
    }
}

// dst[c*rows + r] = src[r*cols + c]
__global__ void transpose_kernel(const float* __restrict__ src, float* __restrict__ dst,
                                 int rows, int cols) {
    int idx = blockIdx.x * 256 + threadIdx.x;
    if (idx < rows * cols) {
        int r = idx / cols, c = idx - r * cols;
        dst[c * rows + r] = src[idx];
    }
}

// ---------------- lin0: out = relu(x @ lin0_w.T + b) ----------------
__global__ void lin0_kernel(const float* __restrict__ x, const float* __restrict__ w,
                            const float* __restrict__ b, float* __restrict__ out) {
    int grp = threadIdx.x >> 6;
    int d = threadIdx.x & 63;
    int n = blockIdx.x * 4 + grp;
    __shared__ float xs[4][NF];
    int t = threadIdx.x;
    if (t < 4 * NF) {
        int r = t / NF, c = t - r * NF;
        int nn2 = blockIdx.x * 4 + r;
        xs[r][c] = (nn2 < NN) ? x[nn2 * NF + c] : 0.f;
    }
    __syncthreads();
    if (n >= NN) return;
    float acc = b[d];
#pragma unroll
    for (int k = 0; k < NF; k++) acc += xs[grp][k] * w[d * NF + k];
    out[n * D + d] = fmaxf(acc, 0.f);
}

// ================= MFMA fused message kernel (r11 structure; Bs stride 132 = conflict-free) =================
// 512 threads = 8 waves. wave = (half = wid>>2: edges half*64..+63, ct = wid&3: o-cols ct*16..+15).
// Each wave: 4 row-tiles (afr 64 regs, i-invariant). W2 slices staged via reg-prefetch ->
// double-buffered LDS Bs; ONE barrier per i. Fixup multipliers: f32 hsrcT[i][e], b128 broadcast.
// Bs row stride 132 elem (264 B ≡ 8 mod 128): B-frag 16B chunks land on distinct bank-groups
// across n-lanes (was 8-way conflicted at stride 136).
__global__ __launch_bounds__(512, 4) void msg_mfma_kernel(
    const float* __restrict__ h, const float* __restrict__ ea,
    const float* __restrict__ w1, const float* __restrict__ b1,
    const __hip_bfloat16* __restrict__ w2r,  // bf16 nn_w2 [4096][128] row-major = [i][o][k]
    const float* __restrict__ b2, const int* __restrict__ ei,
    float* __restrict__ agg)
{
    // pool: hid[128][136] bf16 (preamble, 34816 B) aliases Bs[2][64][132] bf16 (33792 B) and B2s
    __shared__ __align__(16) char upool[34816];
    __hip_bfloat16 (*hid)[136] = (__hip_bfloat16(*)[136])upool;
    __hip_bfloat16 (*Bs)[64][132] = (__hip_bfloat16(*)[64][132])upool;
    __hip_bfloat16 (*B2s)[72] = (__hip_bfloat16(*)[72])upool;
    __shared__ __align__(16) float hsrcT[64][132];  // hsrcT[i][e] = h[src_e][i], f32
    __shared__ float w1s[128][4];
    __shared__ float b1s[128];
    __shared__ int didx[EB];

    int tid = threadIdx.x;
    int e0 = blockIdx.x * EB;

    if (tid < EB) {
        didx[tid] = (e0 + tid < NE) ? ei[NE + e0 + tid] : -1;
    } else if (tid < EB + 128) {
        int k = tid - EB;
        w1s[k][0] = w1[k * 4 + 0]; w1s[k][1] = w1[k * 4 + 1];
        w1s[k][2] = w1[k * 4 + 2]; w1s[k][3] = w1[k * 4 + 3];
        b1s[k] = b1[k];
    }
    // --- gather h[src] -> hsrcT (transposed f32); 4 threads per edge ---
    {
        int e = tid >> 2, seg = (tid & 3) * 16;
        int ge = e0 + e;
        int src = (ge < NE) ? ei[ge] : 0;
        const float4* hp = (const float4*)(h + (size_t)src * 64 + seg);
#pragma unroll
        for (int u = 0; u < 4; u++) {
            float4 v = (ge < NE) ? hp[u] : make_float4(0.f, 0.f, 0.f, 0.f);
            hsrcT[seg + u * 4 + 0][e] = v.x;
            hsrcT[seg + u * 4 + 1][e] = v.y;
            hsrcT[seg + u * 4 + 2][e] = v.z;
            hsrcT[seg + u * 4 + 3][e] = v.w;
        }
    }
    __syncthreads();  // w1s/b1s ready
    // --- hid[e][k] = relu(b1[k] + ea[e]·w1[k]) bf16; 4 threads per edge (32 k each) ---
    {
        int e = tid & 127, kb = (tid >> 7) * 32;
        int ge = e0 + e;
        float4 av = (ge < NE) ? *(const float4*)(ea + (size_t)ge * 4)
                              : make_float4(0.f, 0.f, 0.f, 0.f);
        for (int k = kb; k < kb + 32; k += 4) {
            union { __hip_bfloat16 b[4]; uint2 uu; } pk;
#pragma unroll
            for (int u = 0; u < 4; u++) {
                float v = b1s[k + u] + av.x * w1s[k + u][0] + av.y * w1s[k + u][1] +
                          av.z * w1s[k + u][2] + av.w * w1s[k + u][3];
                pk.b[u] = __float2bfloat16((ge < NE) ? fmaxf(v, 0.f) : 0.f);
            }
            *(uint2*)&hid[e][k] = pk.uu;
        }
    }
    __syncthreads();  // hid ready

    int lane = tid & 63;
    int wid = tid >> 6;
    int half = wid >> 2;
    int ct = wid & 3;
    int n = lane & 15, q = lane >> 4;
    int ocol = ct * 16 + n;

    // A-fragments (i-invariant): 4 row-tiles x 4 k-steps
    bf16x8 afr[4][4];
#pragma unroll
    for (int rt = 0; rt < 4; rt++)
#pragma unroll
        for (int ks = 0; ks < 4; ks++)
            afr[rt][ks] = *(const bf16x8*)&hid[half * 64 + rt * 16 + n][ks * 32 + q * 8];
    __syncthreads();  // hid dead; pool becomes Bs

    // stage Bs[0] (slice i=0): 512 threads x 32 B
    int srow = tid >> 3, sseg = (tid & 7) * 16;
    {
        const bf16x8* gp = (const bf16x8*)(w2r + (size_t)srow * 128 + sseg);
        bf16x8* lp = (bf16x8*)&Bs[0][srow][sseg];
        lp[0] = gp[0]; lp[1] = gp[1];
    }
    __syncthreads();  // Bs[0] ready

    f32x4 acc[4];
#pragma unroll
    for (int rt = 0; rt < 4; rt++) acc[rt] = (f32x4){0.f, 0.f, 0.f, 0.f};

    for (int i = 0; i < 64; i++) {
        const int cur = i & 1;
        bf16x8 pre0, pre1;
        if (i + 1 < 64) {
            const bf16x8* gp = (const bf16x8*)(w2r + (size_t)(i + 1) * 8192 + srow * 128 + sseg);
            pre0 = gp[0]; pre1 = gp[1];
        }
        bf16x8 bfr[4];
#pragma unroll
        for (int ks = 0; ks < 4; ks++)
            bfr[ks] = *(const bf16x8*)&Bs[cur][ocol][ks * 32 + q * 8];
        f32x4 S[4];
#pragma unroll
        for (int rt = 0; rt < 4; rt++) S[rt] = (f32x4){0.f, 0.f, 0.f, 0.f};
#pragma unroll
        for (int ks = 0; ks < 4; ks++)
#pragma unroll
            for (int rt = 0; rt < 4; rt++)
                S[rt] = __builtin_amdgcn_mfma_f32_16x16x32_bf16(afr[rt][ks], bfr[ks], S[rt], 0, 0, 0);
        // fixup: acc[rt] += h[src,i] * S[rt]  (f32x4 broadcast LDS reads)
#pragma unroll
        for (int rt = 0; rt < 4; rt++) {
            f32x4 hm = *(const f32x4*)&hsrcT[i][half * 64 + rt * 16 + q * 4];
#pragma unroll
            for (int r = 0; r < 4; r++) acc[rt][r] += hm[r] * S[rt][r];
        }
        if (i + 1 < 64) {
            bf16x8* lp = (bf16x8*)&Bs[cur ^ 1][srow][sseg];
            lp[0] = pre0; lp[1] = pre1;
        }
        __syncthreads();
    }

    // ---- b2 pass ----
    for (int g2 = tid; g2 < 4096; g2 += 512) {
        B2s[g2 & 63][g2 >> 6] = __float2bfloat16(b2[g2]);
    }
    __syncthreads();
#pragma unroll
    for (int rt = 0; rt < 4; rt++) {
        f32x4 S2 = (f32x4){0.f, 0.f, 0.f, 0.f};
#pragma unroll
        for (int ks2 = 0; ks2 < 2; ks2++) {
            union { __hip_bfloat16 b[8]; bf16x8 v; } pk;
#pragma unroll
            for (int j = 0; j < 8; j++)
                pk.b[j] = __float2bfloat16(hsrcT[ks2 * 32 + q * 8 + j][half * 64 + rt * 16 + n]);
            bf16x8 bfr2 = *(const bf16x8*)&B2s[ocol][ks2 * 32 + q * 8];
            S2 = __builtin_amdgcn_mfma_f32_16x16x32_bf16(pk.v, bfr2, S2, 0, 0, 0);
        }
#pragma unroll
        for (int r = 0; r < 4; r++) acc[rt][r] += S2[r];
    }

    // scatter
#pragma unroll
    for (int rt = 0; rt < 4; rt++)
#pragma unroll
        for (int r = 0; r < 4; r++) {
            int e = half * 64 + rt * 16 + q * 4 + r;
            int dn = didx[e];
            if (dn >= 0) atomicAdd(&agg[(size_t)dn * 64 + ocol], acc[rt][r]);
        }
}

// ---------------- degree ----------------
__global__ void deg_kernel(const int* __restrict__ ei, float* __restrict__ deg) {
    int e = blockIdx.x * 256 + threadIdx.x;
    if (e < NE) atomicAdd(&deg[ei[NE + e]], 1.0f);
}
__global__ void invdeg_kernel(float* deg) {
    int n = blockIdx.x * 256 + threadIdx.x;
    if (n < NN) deg[n] = 1.0f / fmaxf(deg[n], 1.0f);
}

// ---------------- MFMA fused conv + GRU: 64 nodes/block, 256 threads, LDS-staged weights ----------------
__global__ __launch_bounds__(256) void conv_gru_kernel(
    float* __restrict__ h, float* __restrict__ agg, const float* __restrict__ invdeg,
    const __hip_bfloat16* __restrict__ rootB,   // [64 j][64 k]
    const float* __restrict__ cbias,
    const __hip_bfloat16* __restrict__ wihB,    // [192 jg][64 k]
    const __hip_bfloat16* __restrict__ whhB,    // [192 jg][64 k]
    const float* __restrict__ bih, const float* __restrict__ bhh)
{
    __shared__ __align__(16) __hip_bfloat16 wbuf[128][88];
    __shared__ __align__(16) __hip_bfloat16 hsb[64][88];
    __shared__ __align__(16) __hip_bfloat16 msb[64][88];
    int tid = threadIdx.x;
    int lane = tid & 63, wid = tid >> 6;
    int n = lane & 15, q = lane >> 4;
    int n0 = blockIdx.x * 64;

    auto stage64 = [&](const __hip_bfloat16* src, int rowoff) {
        int r = tid >> 2, cb = (tid & 3) * 16;
        const bf16x8* gp = (const bf16x8*)(src + (size_t)r * 64 + cb);
        bf16x8* lp = (bf16x8*)&wbuf[rowoff + r][cb];
        lp[0] = gp[0]; lp[1] = gp[1];
    };
    auto stage128 = [&](const __hip_bfloat16* src) {
        int r = tid >> 1, cb = (tid & 1) * 32;
        const bf16x8* gp = (const bf16x8*)(src + (size_t)r * 64 + cb);
        bf16x8* lp = (bf16x8*)&wbuf[r][cb];
        lp[0] = gp[0]; lp[1] = gp[1]; lp[2] = gp[2]; lp[3] = gp[3];
    };

    {
        int nd = tid >> 2, sg = (tid & 3) * 16;
        int gn = n0 + nd;
        int src = (gn < NN) ? gn : 0;
        const float4* hp = (const float4*)(h + (size_t)src * 64 + sg);
#pragma unroll
        for (int u = 0; u < 4; u++) {
            float4 v = hp[u];
            union { __hip_bfloat16 b[4]; uint2 uu; } pk;
            pk.b[0] = __float2bfloat16(v.x); pk.b[1] = __float2bfloat16(v.y);
            pk.b[2] = __float2bfloat16(v.z); pk.b[3] = __float2bfloat16(v.w);
            *(uint2*)&hsb[nd][sg + u * 4] = pk.uu;
        }
    }
    stage64(rootB, 0);
    __syncthreads();

    int row = wid * 16 + n;
    bf16x8 ah[2];
    ah[0] = *(const bf16x8*)&hsb[row][q * 8];
    ah[1] = *(const bf16x8*)&hsb[row][32 + q * 8];

    f32x4 mm[4];
#pragma unroll
    for (int ct = 0; ct < 4; ct++) mm[ct] = (f32x4){0.f, 0.f, 0.f, 0.f};
#pragma unroll
    for (int ks = 0; ks < 2; ks++)
#pragma unroll
        for (int ct = 0; ct < 4; ct++) {
            bf16x8 b = *(const bf16x8*)&wbuf[ct * 16 + n][ks * 32 + q * 8];
            mm[ct] = __builtin_amdgcn_mfma_f32_16x16x32_bf16(ah[ks], b, mm[ct], 0, 0, 0);
        }
#pragma unroll
    for (int ct = 0; ct < 4; ct++)
#pragma unroll
        for (int r = 0; r < 4; r++) {
            int nd = wid * 16 + q * 4 + r;
            int gn = n0 + nd;
            int j = ct * 16 + n;
            float v = 0.f;
            if (gn < NN) {
                float a = agg[(size_t)gn * 64 + j];
                v = fmaxf(mm[ct][r] + a * invdeg[gn] + cbias[j], 0.f);
                agg[(size_t)gn * 64 + j] = 0.f;
            }
            msb[nd][j] = __float2bfloat16(v);
        }
    __syncthreads();

    bf16x8 am[2];
    am[0] = *(const bf16x8*)&msb[row][q * 8];
    am[1] = *(const bf16x8*)&msb[row][32 + q * 8];

    f32x4 grz[8], gin[4], ghn[4];
#pragma unroll
    for (int ct = 0; ct < 8; ct++) grz[ct] = (f32x4){0.f, 0.f, 0.f, 0.f};
#pragma unroll
    for (int ct = 0; ct < 4; ct++) { gin[ct] = (f32x4){0.f, 0.f, 0.f, 0.f}; ghn[ct] = (f32x4){0.f, 0.f, 0.f, 0.f}; }

    stage128(wihB);
    __syncthreads();
#pragma unroll
    for (int ks = 0; ks < 2; ks++)
#pragma unroll
        for (int ct = 0; ct < 8; ct++) {
            bf16x8 b = *(const bf16x8*)&wbuf[ct * 16 + n][ks * 32 + q * 8];
            grz[ct] = __builtin_amdgcn_mfma_f32_16x16x32_bf16(am[ks], b, grz[ct], 0, 0, 0);
        }
    __syncthreads();

    stage128(whhB);
    __syncthreads();
#pragma unroll
    for (int ks = 0; ks < 2; ks++)
#pragma unroll
        for (int ct = 0; ct < 8; ct++) {
            bf16x8 b = *(const bf16x8*)&wbuf[ct * 16 + n][ks * 32 + q * 8];
            grz[ct] = __builtin_amdgcn_mfma_f32_16x16x32_bf16(ah[ks], b, grz[ct], 0, 0, 0);
        }
    __syncthreads();

    stage64(wihB + 128 * 64, 0);
    stage64(whhB + 128 * 64, 64);
    __syncthreads();
#pragma unroll
    for (int ks = 0; ks < 2; ks++)
#pragma unroll
        for (int ct = 0; ct < 4; ct++) {
            bf16x8 bi = *(const bf16x8*)&wbuf[ct * 16 + n][ks * 32 + q * 8];
            gin[ct] = __builtin_amdgcn_mfma_f32_16x16x32_bf16(am[ks], bi, gin[ct], 0, 0, 0);
            bf16x8 bh = *(const bf16x8*)&wbuf[64 + ct * 16 + n][ks * 32 + q * 8];
            ghn[ct] = __builtin_amdgcn_mfma_f32_16x16x32_bf16(ah[ks], bh, ghn[ct], 0, 0, 0);
        }

#pragma unroll
    for (int ct = 0; ct < 4; ct++) {
        int jr = ct * 16 + n, jz = 64 + jr, jn = 128 + jr;
        float br_ = bih[jr] + bhh[jr];
        float bz_ = bih[jz] + bhh[jz];
        float bin_ = bih[jn], bhn_ = bhh[jn];
#pragma unroll
        for (int r = 0; r < 4; r++) {
            int gn = n0 + wid * 16 + q * 4 + r;
            if (gn >= NN) continue;
            float rr = sigmoidf(grz[ct][r] + br_);
            float zz = sigmoidf(grz[ct + 4][r] + bz_);
            float nv = tanhf(gin[ct][r] + bin_ + rr * (ghn[ct][r] + bhn_));
            float hv = h[(size_t)gn * 64 + jr];
            h[(size_t)gn * 64 + jr] = (1.f - zz) * nv + zz * hv;
        }
    }
}

// ---------------- graph starts (batch sorted) ----------------
__global__ void starts_kernel(const int* __restrict__ batch, int* __restrict__ start) {
    int n = blockIdx.x * 256 + threadIdx.x;
    if (n >= NN) return;
    int b = batch[n];
    int bp = (n == 0) ? -1 : batch[n - 1];
    for (int g = bp + 1; g <= b; g++) start[g] = n;
    if (n == NN - 1) {
        for (int g = b + 1; g <= NG; g++) start[g] = NN;
    }
}

// ---------------- fused Set2Set step: LSTM + attention + pooling ----------------
__global__ void s2s_step_kernel(float* __restrict__ qstar, float* __restrict__ hh,
                                float* __restrict__ cc, const float* __restrict__ wihT,
                                const float* __restrict__ whhT, const float* __restrict__ bih,
                                const float* __restrict__ bhh, const float* __restrict__ out,
                                const int* __restrict__ start) {
    int g = blockIdx.x;
    int tid = threadIdx.x;  // 256
    __shared__ float qv[128], hsh[64], gates[256], hnew[64];
    __shared__ float red[4][64];
    __shared__ float mxS[4], seS[4];
    if (tid < 128) qv[tid] = qstar[g * 128 + tid];
    if (tid < 64) hsh[tid] = hh[g * 64 + tid];
    __syncthreads();
    float acc = bih[tid] + bhh[tid];
#pragma unroll 8
    for (int k = 0; k < 128; k++) acc = fmaf(qv[k], wihT[k * 256 + tid], acc);
#pragma unroll 8
    for (int k = 0; k < 64; k++) acc = fmaf(hsh[k], whhT[k * 256 + tid], acc);
    gates[tid] = acc;
    __syncthreads();
    if (tid < 64) {
        float gi = gates[tid], gf = gates[64 + tid], gg = gates[128 + tid], go = gates[192 + tid];
        float c2 = sigmoidf(gf) * cc[g * 64 + tid] + sigmoidf(gi) * tanhf(gg);
        float h2 = sigmoidf(go) * tanhf(c2);
        cc[g * 64 + tid] = c2;
        hh[g * 64 + tid] = h2;
        hnew[tid] = h2;
    }
    __syncthreads();
    int d = tid & 63, sub = tid >> 6;
    int n0 = start[g], n1 = start[g + 1];
    float hd = hnew[d];
    float mx = -INFINITY;
    for (int nn2 = n0 + sub; nn2 < n1; nn2 += 4) {
        float p = out[nn2 * D + d] * hd;
#pragma unroll
        for (int off = 32; off; off >>= 1) p += __shfl_xor(p, off);
        mx = fmaxf(mx, p);
    }
    if (d == 0) mxS[sub] = mx;
    __syncthreads();
    mx = fmaxf(fmaxf(mxS[0], mxS[1]), fmaxf(mxS[2], mxS[3]));
    float sexp = 0.f, racc = 0.f;
    for (int nn2 = n0 + sub; nn2 < n1; nn2 += 4) {
        float ond = out[nn2 * D + d];
        float p = ond * hd;
#pragma unroll
        for (int off = 32; off; off >>= 1) p += __shfl_xor(p, off);
        float a = expf(p - mx);
        sexp += a;
        racc = fmaf(a, ond, racc);
    }
    red[sub][d] = racc;
    if (d == 0) seS[sub] = sexp;
    __syncthreads();
    if (sub == 0) {
        float rtot = red[0][d] + red[1][d] + red[2][d] + red[3][d];
        float stot = seS[0] + seS[1] + seS[2] + seS[3];
        float r = rtot / (stot + 1e-16f);
        qstar[g * 128 + d] = hd;
        qstar[g * 128 + 64 + d] = r;
    }
}

// ---------------- head ----------------
__global__ void final_kernel(const float* __restrict__ qstar, const float* __restrict__ w1,
                             const float* __restrict__ b1, const float* __restrict__ w2,
                             const float* __restrict__ b2, float* __restrict__ y) {
    int g = blockIdx.x;
    int d = threadIdx.x;  // 64
    __shared__ float q[128];
    q[d] = qstar[g * 128 + d];
    q[64 + d] = qstar[g * 128 + 64 + d];
    __syncthreads();
    float acc = b1[d];
#pragma unroll 8
    for (int k = 0; k < 128; k++) acc = fmaf(q[k], w1[d * 128 + k], acc);
    acc = fmaxf(acc, 0.f);
    float p = acc * w2[d];
#pragma unroll
    for (int off = 32; off; off >>= 1) p += __shfl_xor(p, off);
    if (d == 0) y[g] = p + b2[0];
}

extern "C" void kernel_launch(void* const* d_in, const int* in_sizes, int n_in,
                              void* d_out, int out_size, void* d_ws, size_t ws_size,
                              hipStream_t stream) {
    (void)in_sizes; (void)n_in; (void)out_size; (void)ws_size;
    const float* x = (const float*)d_in[0];
    const int* edge_index = (const int*)d_in[1];
    const float* edge_attr = (const float*)d_in[2];
    const int* batch = (const int*)d_in[3];
    const float* lin0_w = (const float*)d_in[4];
    const float* lin0_b = (const float*)d_in[5];
    const float* nn_w1 = (const float*)d_in[6];
    const float* nn_b1 = (const float*)d_in[7];
    const float* nn_w2 = (const float*)d_in[8];
    const float* nn_b2 = (const float*)d_in[9];
    const float* conv_root = (const float*)d_in[10];
    const float* conv_bias = (const float*)d_in[11];
    const float* gru_w_ih = (const float*)d_in[12];
    const float* gru_w_hh = (const float*)d_in[13];
    const float* gru_b_ih = (const float*)d_in[14];
    const float* gru_b_hh = (const float*)d_in[15];
    const float* s2s_w_ih = (const float*)d_in[16];
    const float* s2s_w_hh = (const float*)d_in[17];
    const float* s2s_b_ih = (const float*)d_in[18];
    const float* s2s_b_hh = (const float*)d_in[19];
    const float* lin1_w = (const float*)d_in[20];
    const float* lin1_b = (const float*)d_in[21];
    const float* lin2_w = (const float*)d_in[22];
    const float* lin2_b = (const float*)d_in[23];
    float* y = (float*)d_out;

    char* ws = (char*)d_ws;
    size_t off = 0;
    auto alloc = [&](size_t bytes) {
        void* p = ws + off;
        off = (off + bytes + 255) & ~(size_t)255;
        return p;
    };
    float* h = (float*)alloc((size_t)NN * D * 4);
    float* agg = (float*)alloc((size_t)NN * D * 4);
    float* invdeg = (float*)alloc((size_t)NN * 4);
    int* start = (int*)alloc((size_t)(NG + 1) * 4);
    float* qstar = (float*)alloc((size_t)NG * 128 * 4);   // 1 MB; ALIASED as w2r during MP phase
    float* hh = (float*)alloc((size_t)NG * 64 * 4);
    float* ccv = (float*)alloc((size_t)NG * 64 * 4);
    float* s2sT_ih = (float*)alloc(256 * 128 * 4);
    float* s2sT_hh = (float*)alloc(256 * 64 * 4);
    __hip_bfloat16* rootB = (__hip_bfloat16*)alloc(64 * 64 * 2);
    __hip_bfloat16* wihB = (__hip_bfloat16*)alloc(192 * 64 * 2);
    __hip_bfloat16* whhB = (__hip_bfloat16*)alloc(192 * 64 * 2);
    __hip_bfloat16* w2r = (__hip_bfloat16*)qstar;

    // prep
    hipMemsetAsync(invdeg, 0, (size_t)NN * 4, stream);
    hipMemsetAsync(agg, 0, (size_t)NN * D * 4, stream);
    transpose_kernel<<<(256 * 128 + 255) / 256, 256, 0, stream>>>(s2s_w_ih, s2sT_ih, 256, 128);
    transpose_kernel<<<(256 * 64 + 255) / 256, 256, 0, stream>>>(s2s_w_hh, s2sT_hh, 256, 64);
    cvt_bf16_kernel<<<(64 * 8192 + 255) / 256, 256, 0, stream>>>(nn_w2, w2r, 64 * 8192);
    cvt_bf16_kernel<<<(192 * 64 + 255) / 256, 256, 0, stream>>>(gru_w_ih, wihB, 192 * 64);
    cvt_bf16_kernel<<<(192 * 64 + 255) / 256, 256, 0, stream>>>(gru_w_hh, whhB, 192 * 64);
    tcast_bf16_kernel<<<(64 * 64 + 255) / 256, 256, 0, stream>>>(conv_root, rootB, 64, 64);
    lin0_kernel<<<NN / 4, 256, 0, stream>>>(x, lin0_w, lin0_b, h);
    deg_kernel<<<(NE + 255) / 256, 256, 0, stream>>>(edge_index, invdeg);
    invdeg_kernel<<<(NN + 255) / 256, 256, 0, stream>>>(invdeg);
    starts_kernel<<<(NN + 255) / 256, 256, 0, stream>>>(batch, start);

    // 3 message-passing + conv+GRU iterations (conv_gru re-zeroes agg for the next msg)
    for (int it = 0; it < 3; it++) {
        msg_mfma_kernel<<<(NE + EB - 1) / EB, 512, 0, stream>>>(
            h, edge_attr, nn_w1, nn_b1, w2r, nn_b2, edge_index, agg);
        conv_gru_kernel<<<(NN + 63) / 64, 256, 0, stream>>>(
            h, agg, invdeg, rootB, conv_bias, wihB, whhB, gru_b_ih, gru_b_hh);
    }

    // Set2Set (qstar region no longer needed as w2r)
    hipMemsetAsync(qstar, 0, (size_t)NG * 128 * 4, stream);
    hipMemsetAsync(hh, 0, (size_t)NG * 64 * 4, stream);
    hipMemsetAsync(ccv, 0, (size_t)NG * 64 * 4, stream);
    for (int t = 0; t < 3; t++) {
        s2s_step_kernel<<<NG, 256, 0, stream>>>(qstar, hh, ccv, s2sT_ih, s2sT_hh,
                                                s2s_b_ih, s2s_b_hh, h, start);
    }
    final_kernel<<<NG, 64, 0, stream>>>(qstar, lin1_w, lin1_b, lin2_w, lin2_b, y);
}

// Round 13
// 669.345 us; speedup vs baseline: 1.9541x; 1.9541x over previous
//
#include <hip/hip_runtime.h>
#include <hip/hip_bf16.h>

#define NN 50000    // nodes
#define NE 100000   // edges
#define NG 2048     // graphs
#define NF 14
#define D 64
#define EB 128      // edges per block in msg kernel

typedef __attribute__((ext_vector_type(8))) short bf16x8;
typedef __attribute__((ext_vector_type(4))) float f32x4;

__device__ __forceinline__ float sigmoidf(float x) { return 1.f / (1.f + expf(-x)); }

// ---------------- fused prep: all weight casts/transposes in one launch ----------------
// flat regions: w2 cast(524288) | wih cast(12288) | whh cast(12288) | root tcast(4096)
//             | s2s_ih T(32768) | s2s_hh T(16384)   => 602112 elems = 2352 blocks x 256
__global__ void prep_kernel(const float* __restrict__ nn_w2, __hip_bfloat16* __restrict__ w2r,
                            const float* __restrict__ gru_w_ih, __hip_bfloat16* __restrict__ wihB,
                            const float* __restrict__ gru_w_hh, __hip_bfloat16* __restrict__ whhB,
                            const float* __restrict__ conv_root, __hip_bfloat16* __restrict__ rootB,
                            const float* __restrict__ s2s_w_ih, float* __restrict__ s2sT_ih,
                            const float* __restrict__ s2s_w_hh, float* __restrict__ s2sT_hh) {
    int idx = blockIdx.x * 256 + threadIdx.x;
    if (idx < 524288) { w2r[idx] = __float2bfloat16(nn_w2[idx]); return; }
    idx -= 524288;
    if (idx < 12288) { wihB[idx] = __float2bfloat16(gru_w_ih[idx]); return; }
    idx -= 12288;
    if (idx < 12288) { whhB[idx] = __float2bfloat16(gru_w_hh[idx]); return; }
    idx -= 12288;
    if (idx < 4096) {
        int r = idx >> 6, c = idx & 63;
        rootB[c * 64 + r] = __float2bfloat16(conv_root[idx]);
        return;
    }
    idx -= 4096;
    if (idx < 32768) {
        int r = idx >> 7, c = idx & 127;
        s2sT_ih[c * 256 + r] = s2s_w_ih[idx];
        return;
    }
    idx -= 32768;
    if (idx < 16384) {
        int r = idx >> 6, c = idx & 63;
        s2sT_hh[c * 256 + r] = s2s_w_hh[idx];
    }
}

// ---------------- lin0: out = relu(x @ lin0_w.T + b) ----------------
__global__ void lin0_kernel(const float* __restrict__ x, const float* __restrict__ w,
                            const float* __restrict__ b, float* __restrict__ out) {
    int grp = threadIdx.x >> 6;
    int d = threadIdx.x & 63;
    int n = blockIdx.x * 4 + grp;
    __shared__ float xs[4][NF];
    int t = threadIdx.x;
    if (t < 4 * NF) {
        int r = t / NF, c = t - r * NF;
        int nn2 = blockIdx.x * 4 + r;
        xs[r][c] = (nn2 < NN) ? x[nn2 * NF + c] : 0.f;
    }
    __syncthreads();
    if (n >= NN) return;
    float acc = b[d];
#pragma unroll
    for (int k = 0; k < NF; k++) acc += xs[grp][k] * w[d * NF + k];
    out[n * D + d] = fmaxf(acc, 0.f);
}

// ---------------- merged degree + graph starts ----------------
__global__ void deg_starts_kernel(const int* __restrict__ ei, const int* __restrict__ batch,
                                  float* __restrict__ deg, int* __restrict__ start) {
    int i = blockIdx.x * 256 + threadIdx.x;
    if (i < NE) atomicAdd(&deg[ei[NE + i]], 1.0f);
    if (i < NN) {
        int b = batch[i];
        int bp = (i == 0) ? -1 : batch[i - 1];
        for (int g = bp + 1; g <= b; g++) start[g] = i;
        if (i == NN - 1) {
            for (int g = b + 1; g <= NG; g++) start[g] = NN;
        }
    }
}

// ================= MFMA fused message kernel (r11-proven: stride 136, f32 hsrcT) =================
__global__ __launch_bounds__(512, 4) void msg_mfma_kernel(
    const float* __restrict__ h, const float* __restrict__ ea,
    const float* __restrict__ w1, const float* __restrict__ b1,
    const __hip_bfloat16* __restrict__ w2r,  // bf16 nn_w2 [4096][128] row-major = [i][o][k]
    const float* __restrict__ b2, const int* __restrict__ ei,
    float* __restrict__ agg)
{
    // pool: hid[128][136] bf16 (preamble) aliases Bs[2][64][136] bf16 (main loop) and B2s (b2 pass)
    __shared__ __align__(16) char upool[34816];
    __hip_bfloat16 (*hid)[136] = (__hip_bfloat16(*)[136])upool;
    __hip_bfloat16 (*Bs)[64][136] = (__hip_bfloat16(*)[64][136])upool;
    __hip_bfloat16 (*B2s)[72] = (__hip_bfloat16(*)[72])upool;
    __shared__ __align__(16) float hsrcT[64][132];  // hsrcT[i][e] = h[src_e][i], f32
    __shared__ float w1s[128][4];
    __shared__ float b1s[128];
    __shared__ int didx[EB];

    int tid = threadIdx.x;
    int e0 = blockIdx.x * EB;

    if (tid < EB) {
        didx[tid] = (e0 + tid < NE) ? ei[NE + e0 + tid] : -1;
    } else if (tid < EB + 128) {
        int k = tid - EB;
        w1s[k][0] = w1[k * 4 + 0]; w1s[k][1] = w1[k * 4 + 1];
        w1s[k][2] = w1[k * 4 + 2]; w1s[k][3] = w1[k * 4 + 3];
        b1s[k] = b1[k];
    }
    // --- gather h[src] -> hsrcT (transposed f32); 4 threads per edge ---
    {
        int e = tid >> 2, seg = (tid & 3) * 16;
        int ge = e0 + e;
        int src = (ge < NE) ? ei[ge] : 0;
        const float4* hp = (const float4*)(h + (size_t)src * 64 + seg);
#pragma unroll
        for (int u = 0; u < 4; u++) {
            float4 v = (ge < NE) ? hp[u] : make_float4(0.f, 0.f, 0.f, 0.f);
            hsrcT[seg + u * 4 + 0][e] = v.x;
            hsrcT[seg + u * 4 + 1][e] = v.y;
            hsrcT[seg + u * 4 + 2][e] = v.z;
            hsrcT[seg + u * 4 + 3][e] = v.w;
        }
    }
    __syncthreads();  // w1s/b1s ready
    // --- hid[e][k] = relu(b1[k] + ea[e]·w1[k]) bf16; 4 threads per edge (32 k each) ---
    {
        int e = tid & 127, kb = (tid >> 7) * 32;
        int ge = e0 + e;
        float4 av = (ge < NE) ? *(const float4*)(ea + (size_t)ge * 4)
                              : make_float4(0.f, 0.f, 0.f, 0.f);
        for (int k = kb; k < kb + 32; k += 4) {
            union { __hip_bfloat16 b[4]; uint2 uu; } pk;
#pragma unroll
            for (int u = 0; u < 4; u++) {
                float v = b1s[k + u] + av.x * w1s[k + u][0] + av.y * w1s[k + u][1] +
                          av.z * w1s[k + u][2] + av.w * w1s[k + u][3];
                pk.b[u] = __float2bfloat16((ge < NE) ? fmaxf(v, 0.f) : 0.f);
            }
            *(uint2*)&hid[e][k] = pk.uu;
        }
    }
    __syncthreads();  // hid ready

    int lane = tid & 63;
    int wid = tid >> 6;
    int half = wid >> 2;
    int ct = wid & 3;
    int n = lane & 15, q = lane >> 4;
    int ocol = ct * 16 + n;

    // A-fragments (i-invariant): 4 row-tiles x 4 k-steps
    bf16x8 afr[4][4];
#pragma unroll
    for (int rt = 0; rt < 4; rt++)
#pragma unroll
        for (int ks = 0; ks < 4; ks++)
            afr[rt][ks] = *(const bf16x8*)&hid[half * 64 + rt * 16 + n][ks * 32 + q * 8];
    __syncthreads();  // hid dead; pool becomes Bs

    // stage Bs[0] (slice i=0): 512 threads x 32 B
    int srow = tid >> 3, sseg = (tid & 7) * 16;
    {
        const bf16x8* gp = (const bf16x8*)(w2r + (size_t)srow * 128 + sseg);
        bf16x8* lp = (bf16x8*)&Bs[0][srow][sseg];
        lp[0] = gp[0]; lp[1] = gp[1];
    }
    __syncthreads();  // Bs[0] ready

    f32x4 acc[4];
#pragma unroll
    for (int rt = 0; rt < 4; rt++) acc[rt] = (f32x4){0.f, 0.f, 0.f, 0.f};

    for (int i = 0; i < 64; i++) {
        const int cur = i & 1;
        bf16x8 pre0, pre1;
        if (i + 1 < 64) {
            const bf16x8* gp = (const bf16x8*)(w2r + (size_t)(i + 1) * 8192 + srow * 128 + sseg);
            pre0 = gp[0]; pre1 = gp[1];
        }
        bf16x8 bfr[4];
#pragma unroll
        for (int ks = 0; ks < 4; ks++)
            bfr[ks] = *(const bf16x8*)&Bs[cur][ocol][ks * 32 + q * 8];
        f32x4 S[4];
#pragma unroll
        for (int rt = 0; rt < 4; rt++) S[rt] = (f32x4){0.f, 0.f, 0.f, 0.f};
#pragma unroll
        for (int ks = 0; ks < 4; ks++)
#pragma unroll
            for (int rt = 0; rt < 4; rt++)
                S[rt] = __builtin_amdgcn_mfma_f32_16x16x32_bf16(afr[rt][ks], bfr[ks], S[rt], 0, 0, 0);
        // fixup: acc[rt] += h[src,i] * S[rt]  (f32x4 broadcast LDS reads)
#pragma unroll
        for (int rt = 0; rt < 4; rt++) {
            f32x4 hm = *(const f32x4*)&hsrcT[i][half * 64 + rt * 16 + q * 4];
#pragma unroll
            for (int r = 0; r < 4; r++) acc[rt][r] += hm[r] * S[rt][r];
        }
        if (i + 1 < 64) {
            bf16x8* lp = (bf16x8*)&Bs[cur ^ 1][srow][sseg];
            lp[0] = pre0; lp[1] = pre1;
        }
        __syncthreads();
    }

    // ---- b2 pass ----
    for (int g2 = tid; g2 < 4096; g2 += 512) {
        B2s[g2 & 63][g2 >> 6] = __float2bfloat16(b2[g2]);
    }
    __syncthreads();
#pragma unroll
    for (int rt = 0; rt < 4; rt++) {
        f32x4 S2 = (f32x4){0.f, 0.f, 0.f, 0.f};
#pragma unroll
        for (int ks2 = 0; ks2 < 2; ks2++) {
            union { __hip_bfloat16 b[8]; bf16x8 v; } pk;
#pragma unroll
            for (int j = 0; j < 8; j++)
                pk.b[j] = __float2bfloat16(hsrcT[ks2 * 32 + q * 8 + j][half * 64 + rt * 16 + n]);
            bf16x8 bfr2 = *(const bf16x8*)&B2s[ocol][ks2 * 32 + q * 8];
            S2 = __builtin_amdgcn_mfma_f32_16x16x32_bf16(pk.v, bfr2, S2, 0, 0, 0);
        }
#pragma unroll
        for (int r = 0; r < 4; r++) acc[rt][r] += S2[r];
    }

    // scatter
#pragma unroll
    for (int rt = 0; rt < 4; rt++)
#pragma unroll
        for (int r = 0; r < 4; r++) {
            int e = half * 64 + rt * 16 + q * 4 + r;
            int dn = didx[e];
            if (dn >= 0) atomicAdd(&agg[(size_t)dn * 64 + ocol], acc[rt][r]);
        }
}

// ---------------- MFMA fused conv + GRU: 64 nodes/block, LDS-staged weights, inline inv-degree ----------------
__global__ __launch_bounds__(256) void conv_gru_kernel(
    float* __restrict__ h, float* __restrict__ agg, const float* __restrict__ deg,
    const __hip_bfloat16* __restrict__ rootB,   // [64 j][64 k]
    const float* __restrict__ cbias,
    const __hip_bfloat16* __restrict__ wihB,    // [192 jg][64 k]
    const __hip_bfloat16* __restrict__ whhB,    // [192 jg][64 k]
    const float* __restrict__ bih, const float* __restrict__ bhh)
{
    __shared__ __align__(16) __hip_bfloat16 wbuf[128][88];
    __shared__ __align__(16) __hip_bfloat16 hsb[64][88];
    __shared__ __align__(16) __hip_bfloat16 msb[64][88];
    int tid = threadIdx.x;
    int lane = tid & 63, wid = tid >> 6;
    int n = lane & 15, q = lane >> 4;
    int n0 = blockIdx.x * 64;

    auto stage64 = [&](const __hip_bfloat16* src, int rowoff) {
        int r = tid >> 2, cb = (tid & 3) * 16;
        const bf16x8* gp = (const bf16x8*)(src + (size_t)r * 64 + cb);
        bf16x8* lp = (bf16x8*)&wbuf[rowoff + r][cb];
        lp[0] = gp[0]; lp[1] = gp[1];
    };
    auto stage128 = [&](const __hip_bfloat16* src) {
        int r = tid >> 1, cb = (tid & 1) * 32;
        const bf16x8* gp = (const bf16x8*)(src + (size_t)r * 64 + cb);
        bf16x8* lp = (bf16x8*)&wbuf[r][cb];
        lp[0] = gp[0]; lp[1] = gp[1]; lp[2] = gp[2]; lp[3] = gp[3];
    };

    {
        int nd = tid >> 2, sg = (tid & 3) * 16;
        int gn = n0 + nd;
        int src = (gn < NN) ? gn : 0;
        const float4* hp = (const float4*)(h + (size_t)src * 64 + sg);
#pragma unroll
        for (int u = 0; u < 4; u++) {
            float4 v = hp[u];
            union { __hip_bfloat16 b[4]; uint2 uu; } pk;
            pk.b[0] = __float2bfloat16(v.x); pk.b[1] = __float2bfloat16(v.y);
            pk.b[2] = __float2bfloat16(v.z); pk.b[3] = __float2bfloat16(v.w);
            *(uint2*)&hsb[nd][sg + u * 4] = pk.uu;
        }
    }
    stage64(rootB, 0);
    __syncthreads();

    int row = wid * 16 + n;
    bf16x8 ah[2];
    ah[0] = *(const bf16x8*)&hsb[row][q * 8];
    ah[1] = *(const bf16x8*)&hsb[row][32 + q * 8];

    f32x4 mm[4];
#pragma unroll
    for (int ct = 0; ct < 4; ct++) mm[ct] = (f32x4){0.f, 0.f, 0.f, 0.f};
#pragma unroll
    for (int ks = 0; ks < 2; ks++)
#pragma unroll
        for (int ct = 0; ct < 4; ct++) {
            bf16x8 b = *(const bf16x8*)&wbuf[ct * 16 + n][ks * 32 + q * 8];
            mm[ct] = __builtin_amdgcn_mfma_f32_16x16x32_bf16(ah[ks], b, mm[ct], 0, 0, 0);
        }
#pragma unroll
    for (int r = 0; r < 4; r++) {
        int nd = wid * 16 + q * 4 + r;
        int gn = n0 + nd;
        float idg = (gn < NN) ? (1.0f / fmaxf(deg[gn], 1.0f)) : 0.f;
#pragma unroll
        for (int ct = 0; ct < 4; ct++) {
            int j = ct * 16 + n;
            float v = 0.f;
            if (gn < NN) {
                float a = agg[(size_t)gn * 64 + j];
                v = fmaxf(mm[ct][r] + a * idg + cbias[j], 0.f);
                agg[(size_t)gn * 64 + j] = 0.f;
            }
            msb[nd][j] = __float2bfloat16(v);
        }
    }
    __syncthreads();

    bf16x8 am[2];
    am[0] = *(const bf16x8*)&msb[row][q * 8];
    am[1] = *(const bf16x8*)&msb[row][32 + q * 8];

    f32x4 grz[8], gin[4], ghn[4];
#pragma unroll
    for (int ct = 0; ct < 8; ct++) grz[ct] = (f32x4){0.f, 0.f, 0.f, 0.f};
#pragma unroll
    for (int ct = 0; ct < 4; ct++) { gin[ct] = (f32x4){0.f, 0.f, 0.f, 0.f}; ghn[ct] = (f32x4){0.f, 0.f, 0.f, 0.f}; }

    stage128(wihB);
    __syncthreads();
#pragma unroll
    for (int ks = 0; ks < 2; ks++)
#pragma unroll
        for (int ct = 0; ct < 8; ct++) {
            bf16x8 b = *(const bf16x8*)&wbuf[ct * 16 + n][ks * 32 + q * 8];
            grz[ct] = __builtin_amdgcn_mfma_f32_16x16x32_bf16(am[ks], b, grz[ct], 0, 0, 0);
        }
    __syncthreads();

    stage128(whhB);
    __syncthreads();
#pragma unroll
    for (int ks = 0; ks < 2; ks++)
#pragma unroll
        for (int ct = 0; ct < 8; ct++) {
            bf16x8 b = *(const bf16x8*)&wbuf[ct * 16 + n][ks * 32 + q * 8];
            grz[ct] = __builtin_amdgcn_mfma_f32_16x16x32_bf16(ah[ks], b, grz[ct], 0, 0, 0);
        }
    __syncthreads();

    stage64(wihB + 128 * 64, 0);
    stage64(whhB + 128 * 64, 64);
    __syncthreads();
#pragma unroll
    for (int ks = 0; ks < 2; ks++)
#pragma unroll
        for (int ct = 0; ct < 4; ct++) {
            bf16x8 bi = *(const bf16x8*)&wbuf[ct * 16 + n][ks * 32 + q * 8];
            gin[ct] = __builtin_amdgcn_mfma_f32_16x16x32_bf16(am[ks], bi, gin[ct], 0, 0, 0);
            bf16x8 bh = *(const bf16x8*)&wbuf[64 + ct * 16 + n][ks * 32 + q * 8];
            ghn[ct] = __builtin_amdgcn_mfma_f32_16x16x32_bf16(ah[ks], bh, ghn[ct], 0, 0, 0);
        }

#pragma unroll
    for (int ct = 0; ct < 4; ct++) {
        int jr = ct * 16 + n, jz = 64 + jr, jn = 128 + jr;
        float br_ = bih[jr] + bhh[jr];
        float bz_ = bih[jz] + bhh[jz];
        float bin_ = bih[jn], bhn_ = bhh[jn];
#pragma unroll
        for (int r = 0; r < 4; r++) {
            int gn = n0 + wid * 16 + q * 4 + r;
            if (gn >= NN) continue;
            float rr = sigmoidf(grz[ct][r] + br_);
            float zz = sigmoidf(grz[ct + 4][r] + bz_);
            float nv = tanhf(gin[ct][r] + bin_ + rr * (ghn[ct][r] + bhn_));
            float hv = h[(size_t)gn * 64 + jr];
            h[(size_t)gn * 64 + jr] = (1.f - zz) * nv + zz * hv;
        }
    }
}

// ---------------- fused Set2Set step: LSTM + attention + pooling (+ head on last step) ----------------
__global__ void s2s_step_kernel(float* __restrict__ qstar, float* __restrict__ hh,
                                float* __restrict__ cc, const float* __restrict__ wihT,
                                const float* __restrict__ whhT, const float* __restrict__ bih,
                                const float* __restrict__ bhh, const float* __restrict__ out,
                                const int* __restrict__ start,
                                const float* __restrict__ lin1_w, const float* __restrict__ lin1_b,
                                const float* __restrict__ lin2_w, const float* __restrict__ lin2_b,
                                float* __restrict__ y, int last) {
    int g = blockIdx.x;
    int tid = threadIdx.x;  // 256
    __shared__ float qv[128], hsh[64], gates[256], hnew[64], rbuf[64];
    __shared__ float red[4][64];
    __shared__ float mxS[4], seS[4];
    if (tid < 128) qv[tid] = qstar[g * 128 + tid];
    if (tid < 64) hsh[tid] = hh[g * 64 + tid];
    __syncthreads();
    float acc = bih[tid] + bhh[tid];
#pragma unroll 8
    for (int k = 0; k < 128; k++) acc = fmaf(qv[k], wihT[k * 256 + tid], acc);
#pragma unroll 8
    for (int k = 0; k < 64; k++) acc = fmaf(hsh[k], whhT[k * 256 + tid], acc);
    gates[tid] = acc;
    __syncthreads();
    if (tid < 64) {
        float gi = gates[tid], gf = gates[64 + tid], gg = gates[128 + tid], go = gates[192 + tid];
        float c2 = sigmoidf(gf) * cc[g * 64 + tid] + sigmoidf(gi) * tanhf(gg);
        float h2 = sigmoidf(go) * tanhf(c2);
        cc[g * 64 + tid] = c2;
        hh[g * 64 + tid] = h2;
        hnew[tid] = h2;
    }
    __syncthreads();
    int d = tid & 63, sub = tid >> 6;
    int n0 = start[g], n1 = start[g + 1];
    float hd = hnew[d];
    float mx = -INFINITY;
    for (int nn2 = n0 + sub; nn2 < n1; nn2 += 4) {
        float p = out[nn2 * D + d] * hd;
#pragma unroll
        for (int off = 32; off; off >>= 1) p += __shfl_xor(p, off);
        mx = fmaxf(mx, p);
    }
    if (d == 0) mxS[sub] = mx;
    __syncthreads();
    mx = fmaxf(fmaxf(mxS[0], mxS[1]), fmaxf(mxS[2], mxS[3]));
    float sexp = 0.f, racc = 0.f;
    for (int nn2 = n0 + sub; nn2 < n1; nn2 += 4) {
        float ond = out[nn2 * D + d];
        float p = ond * hd;
#pragma unroll
        for (int off = 32; off; off >>= 1) p += __shfl_xor(p, off);
        float a = expf(p - mx);
        sexp += a;
        racc = fmaf(a, ond, racc);
    }
    red[sub][d] = racc;
    if (d == 0) seS[sub] = sexp;
    __syncthreads();
    if (sub == 0) {  // wave 0 only: no further barriers (same-wave LDS ordering suffices)
        float rtot = red[0][d] + red[1][d] + red[2][d] + red[3][d];
        float stot = seS[0] + seS[1] + seS[2] + seS[3];
        float r = rtot / (stot + 1e-16f);
        qstar[g * 128 + d] = hd;
        qstar[g * 128 + 64 + d] = r;
        if (last) {
            rbuf[d] = r;
            float a2 = lin1_b[d];
#pragma unroll 8
            for (int k = 0; k < 64; k++) a2 = fmaf(hnew[k], lin1_w[d * 128 + k], a2);
#pragma unroll 8
            for (int k = 0; k < 64; k++) a2 = fmaf(rbuf[k], lin1_w[d * 128 + 64 + k], a2);
            a2 = fmaxf(a2, 0.f);
            float p = a2 * lin2_w[d];
#pragma unroll
            for (int off = 32; off; off >>= 1) p += __shfl_xor(p, off);
            if (d == 0) y[g] = p + lin2_b[0];
        }
    }
}

extern "C" void kernel_launch(void* const* d_in, const int* in_sizes, int n_in,
                              void* d_out, int out_size, void* d_ws, size_t ws_size,
                              hipStream_t stream) {
    (void)in_sizes; (void)n_in; (void)out_size; (void)ws_size;
    const float* x = (const float*)d_in[0];
    const int* edge_index = (const int*)d_in[1];
    const float* edge_attr = (const float*)d_in[2];
    const int* batch = (const int*)d_in[3];
    const float* lin0_w = (const float*)d_in[4];
    const float* lin0_b = (const float*)d_in[5];
    const float* nn_w1 = (const float*)d_in[6];
    const float* nn_b1 = (const float*)d_in[7];
    const float* nn_w2 = (const float*)d_in[8];
    const float* nn_b2 = (const float*)d_in[9];
    const float* conv_root = (const float*)d_in[10];
    const float* conv_bias = (const float*)d_in[11];
    const float* gru_w_ih = (const float*)d_in[12];
    const float* gru_w_hh = (const float*)d_in[13];
    const float* gru_b_ih = (const float*)d_in[14];
    const float* gru_b_hh = (const float*)d_in[15];
    const float* s2s_w_ih = (const float*)d_in[16];
    const float* s2s_w_hh = (const float*)d_in[17];
    const float* s2s_b_ih = (const float*)d_in[18];
    const float* s2s_b_hh = (const float*)d_in[19];
    const float* lin1_w = (const float*)d_in[20];
    const float* lin1_b = (const float*)d_in[21];
    const float* lin2_w = (const float*)d_in[22];
    const float* lin2_b = (const float*)d_in[23];
    float* y = (float*)d_out;

    char* ws = (char*)d_ws;
    size_t off = 0;
    auto alloc = [&](size_t bytes) {
        void* p = ws + off;
        off = (off + bytes + 255) & ~(size_t)255;
        return p;
    };
    float* h = (float*)alloc((size_t)NN * D * 4);
    float* agg = (float*)alloc((size_t)NN * D * 4);
    float* deg = (float*)alloc((size_t)NN * 4);
    int* start = (int*)alloc((size_t)(NG + 1) * 4);
    float* qstar = (float*)alloc((size_t)NG * 128 * 4);   // 1 MB; ALIASED as w2r during MP phase
    float* hh = (float*)alloc((size_t)NG * 64 * 4);       // contiguous with qstar/ccv for single memset
    float* ccv = (float*)alloc((size_t)NG * 64 * 4);
    float* s2sT_ih = (float*)alloc(256 * 128 * 4);
    float* s2sT_hh = (float*)alloc(256 * 64 * 4);
    __hip_bfloat16* rootB = (__hip_bfloat16*)alloc(64 * 64 * 2);
    __hip_bfloat16* wihB = (__hip_bfloat16*)alloc(192 * 64 * 2);
    __hip_bfloat16* whhB = (__hip_bfloat16*)alloc(192 * 64 * 2);
    __hip_bfloat16* w2r = (__hip_bfloat16*)qstar;

    // prep (2 memsets + 3 kernels)
    hipMemsetAsync(deg, 0, (size_t)NN * 4, stream);
    hipMemsetAsync(agg, 0, (size_t)NN * D * 4, stream);
    prep_kernel<<<2352, 256, 0, stream>>>(nn_w2, w2r, gru_w_ih, wihB, gru_w_hh, whhB,
                                          conv_root, rootB, s2s_w_ih, s2sT_ih, s2s_w_hh, s2sT_hh);
    lin0_kernel<<<NN / 4, 256, 0, stream>>>(x, lin0_w, lin0_b, h);
    deg_starts_kernel<<<(NE + 255) / 256, 256, 0, stream>>>(edge_index, batch, deg, start);

    // 3 message-passing + conv+GRU iterations (conv_gru re-zeroes agg for the next msg)
    for (int it = 0; it < 3; it++) {
        msg_mfma_kernel<<<(NE + EB - 1) / EB, 512, 0, stream>>>(
            h, edge_attr, nn_w1, nn_b1, w2r, nn_b2, edge_index, agg);
        conv_gru_kernel<<<(NN + 63) / 64, 256, 0, stream>>>(
            h, agg, deg, rootB, conv_bias, wihB, whhB, gru_b_ih, gru_b_hh);
    }

    // Set2Set: single memset over contiguous qstar|hh|ccv (2 MB), then 3 fused steps
    hipMemsetAsync(qstar, 0, (size_t)NG * 128 * 4 + (size_t)NG * 64 * 4 * 2, stream);
    for (int t = 0; t < 3; t++) {
        s2s_step_kernel<<<NG, 256, 0, stream>>>(qstar, hh, ccv, s2sT_ih, s2sT_hh,
                                                s2s_b_ih, s2s_b_hh, h, start,
                                                lin1_w, lin1_b, lin2_w, lin2_b, y, t == 2);
    }
}